// Round 3
// baseline (61.947 us; speedup 1.0000x reference)
//
#include <hip/hip_runtime.h>

typedef __attribute__((ext_vector_type(2))) float f32x2;

#define B_SZ   16
#define NPTS   4096
#define QN     4                   // opposite-set quarters
#define QPTS   (NPTS / QN)         // 1024 opp points per quarter
#define NPACK  (QPTS / 2)          // 512 two-point packs
#define PBLK   128                 // threads in part kernel
#define OWN_PT 4                   // own points per thread
#define OWN_PB (PBLK * OWN_PT)     // 512 own points per block
#define CHUNKS (NPTS / OWN_PB)     // 8 own chunks
#define TOT    (2 * B_SZ * NPTS)   // 131072 own points both directions
#define BLK    256                 // threads elsewhere

// packed fp32 fma: d.lo = a.lo*b.lo + c.lo ; d.hi = a.hi*b.hi + c.hi
__device__ __forceinline__ f32x2 pk_fma(f32x2 a, f32x2 b, f32x2 c) {
    f32x2 d;
    asm("v_pk_fma_f32 %0, %1, %2, %3" : "=v"(d) : "v"(a), "v"(b), "v"(c));
    return d;
}

// ---------------- main kernel: partial mins over one opp-quarter -------------
// grid.x = B * CHUNKS * QN = 512, grid.y = 2 (direction)
// LDS pack p (opp points 2p,2p+1): sP[2p]={a0,a1,b0,b1} sP[2p+1]={c0,c1,e0,e1}
// where (a,b,c,e) = (-2x,-2y,-2z,|t|^2).  Pair cost: 1.5 pk_fma + 0.5 min3.
__global__ __launch_bounds__(PBLK, 2) void chamfer_part(
    const float* __restrict__ pred, const float* __restrict__ target,
    float* __restrict__ ws)
{
    __shared__ float4 sP[2 * NPACK];   // 16 KB

    const int dir = blockIdx.y;
    const float* own = (dir == 0) ? pred : target;
    const float* opp = (dir == 0) ? target : pred;

    const int bx    = blockIdx.x;
    const int b     = bx >> 5;         // CHUNKS*QN = 32 blocks per batch
    const int chunk = (bx >> 2) & 7;
    const int q     = bx & 3;
    const int tid   = threadIdx.x;

    // ---- stage quarter q of the opposite set as packs ----
    const float* oppB = opp + ((size_t)b * NPTS + q * QPTS) * 3;
    for (int p = tid; p < NPACK; p += PBLK) {     // 4 iters
        const float* o = oppB + 6 * p;
        float x0 = o[0], y0 = o[1], z0 = o[2];
        float x1 = o[3], y1 = o[4], z1 = o[5];
        sP[2 * p]     = make_float4(-2.f * x0, -2.f * x1, -2.f * y0, -2.f * y1);
        sP[2 * p + 1] = make_float4(-2.f * z0, -2.f * z1,
                                    fmaf(z0, z0, fmaf(y0, y0, x0 * x0)),
                                    fmaf(z1, z1, fmaf(y1, y1, x1 * x1)));
    }
    __syncthreads();

    // ---- 4 own points per thread, coords broadcast into pair registers ----
    const int i0 = chunk * OWN_PB + tid;
    f32x2 px2[OWN_PT], py2[OWN_PT], pz2[OWN_PT];
    float p2[OWN_PT], m[OWN_PT];
    #pragma unroll
    for (int k = 0; k < OWN_PT; ++k) {
        const float* op = own + ((size_t)b * NPTS + i0 + k * PBLK) * 3;
        float x = op[0], y = op[1], z = op[2];
        px2[k] = {x, x}; py2[k] = {y, y}; pz2[k] = {z, z};
        p2[k] = fmaf(z, z, fmaf(y, y, x * x));
        m[k]  = 1e30f;
    }

    // ---- min over the quarter: 2 packs (4 opp points) per iteration ----
    for (int p = 0; p < 2 * NPACK; p += 4) {
        float4 f0 = sP[p + 0];
        float4 f1 = sP[p + 1];
        float4 f2 = sP[p + 2];
        float4 f3 = sP[p + 3];
        f32x2 a0 = {f0.x, f0.y}, b0 = {f0.z, f0.w};
        f32x2 c0 = {f1.x, f1.y}, e0 = {f1.z, f1.w};
        f32x2 a1 = {f2.x, f2.y}, b1 = {f2.z, f2.w};
        f32x2 c1 = {f3.x, f3.y}, e1 = {f3.z, f3.w};
        #pragma unroll
        for (int k = 0; k < OWN_PT; ++k) {
            f32x2 t = pk_fma(c0, pz2[k], e0);
            t = pk_fma(b0, py2[k], t);
            t = pk_fma(a0, px2[k], t);
            m[k] = fminf(fminf(t.x, t.y), m[k]);   // -> v_min3_f32
            f32x2 u = pk_fma(c1, pz2[k], e1);
            u = pk_fma(b1, py2[k], u);
            u = pk_fma(a1, px2[k], u);
            m[k] = fminf(fminf(u.x, u.y), m[k]);
        }
    }

    // ---- ws layout [q][dir][b][own]: coalesced partial-min writes ----
    float* wq = ws + (size_t)q * TOT + ((size_t)dir * B_SZ + b) * NPTS;
    #pragma unroll
    for (int k = 0; k < OWN_PT; ++k)
        wq[i0 + k * PBLK] = m[k] + p2[k];   // +p2 commutes with quarter-min
}

// ---------------- combine kernel: min over quarters, mean-reduce -------------
__global__ __launch_bounds__(BLK) void chamfer_combine(
    const float* __restrict__ ws, float* __restrict__ out)
{
    const int idx = blockIdx.x * BLK + threadIdx.x;   // 0 .. TOT-1
    float v = fminf(fminf(ws[idx],           ws[TOT + idx]),
                    fminf(ws[2 * TOT + idx], ws[3 * TOT + idx]));

    for (int off = 32; off > 0; off >>= 1)
        v += __shfl_down(v, off, 64);

    __shared__ float red[4];
    const int tid = threadIdx.x;
    if ((tid & 63) == 0) red[tid >> 6] = v;
    __syncthreads();
    if (tid == 0) {
        float s = (red[0] + red[1]) + (red[2] + red[3]);
        atomicAdd(out, s * (1.0f / ((float)B_SZ * (float)NPTS)));
    }
}

// ---------------- fallback (round-1 kernel) if ws too small ------------------
__global__ __launch_bounds__(BLK) void chamfer_kernel(
    const float* __restrict__ pred, const float* __restrict__ target,
    float* __restrict__ out)
{
    __shared__ float4 sOpp[NPTS];

    const int dir = blockIdx.y;
    const float* own = (dir == 0) ? pred : target;
    const float* opp = (dir == 0) ? target : pred;

    const int b     = blockIdx.x >> 4;
    const int chunk = blockIdx.x & 15;
    const int tid   = threadIdx.x;

    const float* oppB = opp + (size_t)b * NPTS * 3;
    for (int j = tid; j < NPTS; j += BLK) {
        float x = oppB[3 * j + 0];
        float y = oppB[3 * j + 1];
        float z = oppB[3 * j + 2];
        sOpp[j] = make_float4(-2.0f * x, -2.0f * y, -2.0f * z,
                              fmaf(z, z, fmaf(y, y, x * x)));
    }
    __syncthreads();

    const int i = chunk * BLK + tid;
    const float* op = own + ((size_t)b * NPTS + i) * 3;
    const float px = op[0], py = op[1], pz = op[2];
    const float p2 = fmaf(pz, pz, fmaf(py, py, px * px));

    float m0 = 1e30f, m1 = 1e30f, m2 = 1e30f, m3 = 1e30f;
    for (int j = 0; j < NPTS; j += 8) {
        float4 t0 = sOpp[j + 0];
        float4 t1 = sOpp[j + 1];
        float4 t2 = sOpp[j + 2];
        float4 t3 = sOpp[j + 3];
        float4 t4 = sOpp[j + 4];
        float4 t5 = sOpp[j + 5];
        float4 t6 = sOpp[j + 6];
        float4 t7 = sOpp[j + 7];
        m0 = fminf(m0, fmaf(t0.x, px, fmaf(t0.y, py, fmaf(t0.z, pz, t0.w))));
        m1 = fminf(m1, fmaf(t1.x, px, fmaf(t1.y, py, fmaf(t1.z, pz, t1.w))));
        m2 = fminf(m2, fmaf(t2.x, px, fmaf(t2.y, py, fmaf(t2.z, pz, t2.w))));
        m3 = fminf(m3, fmaf(t3.x, px, fmaf(t3.y, py, fmaf(t3.z, pz, t3.w))));
        m0 = fminf(m0, fmaf(t4.x, px, fmaf(t4.y, py, fmaf(t4.z, pz, t4.w))));
        m1 = fminf(m1, fmaf(t5.x, px, fmaf(t5.y, py, fmaf(t5.z, pz, t5.w))));
        m2 = fminf(m2, fmaf(t6.x, px, fmaf(t6.y, py, fmaf(t6.z, pz, t6.w))));
        m3 = fminf(m3, fmaf(t7.x, px, fmaf(t7.y, py, fmaf(t7.z, pz, t7.w))));
    }
    float v = fminf(fminf(m0, m1), fminf(m2, m3)) + p2;

    for (int off = 32; off > 0; off >>= 1)
        v += __shfl_down(v, off, 64);

    __syncthreads();
    float* red = (float*)sOpp;
    if ((tid & 63) == 0) red[tid >> 6] = v;
    __syncthreads();
    if (tid == 0) {
        float s = (red[0] + red[1]) + (red[2] + red[3]);
        atomicAdd(out, s * (1.0f / ((float)B_SZ * (float)NPTS)));
    }
}

extern "C" void kernel_launch(void* const* d_in, const int* in_sizes, int n_in,
                              void* d_out, int out_size, void* d_ws, size_t ws_size,
                              hipStream_t stream) {
    const float* pred   = (const float*)d_in[0];
    const float* target = (const float*)d_in[1];
    float* out = (float*)d_out;

    hipMemsetAsync(out, 0, sizeof(float), stream);

    const size_t ws_needed = (size_t)QN * TOT * sizeof(float);  // 2 MB
    if (ws_size >= ws_needed) {
        float* ws = (float*)d_ws;
        dim3 grid1(B_SZ * CHUNKS * QN, 2);          // 512 x 2 = 1024 blocks
        chamfer_part<<<grid1, PBLK, 0, stream>>>(pred, target, ws);
        chamfer_combine<<<TOT / BLK, BLK, 0, stream>>>(ws, out);
    } else {
        dim3 grid(B_SZ * (NPTS / BLK), 2);
        chamfer_kernel<<<grid, BLK, 0, stream>>>(pred, target, out);
    }
}

// Round 4
// 56.921 us; speedup vs baseline: 1.0883x; 1.0883x over previous
//
#include <hip/hip_runtime.h>

typedef __attribute__((ext_vector_type(2))) float f32x2;

#define B_SZ   16
#define NPTS   4096
#define QN     16                  // opposite-set slices
#define QPTS   (NPTS / QN)         // 256 opp points per slice
#define NPACK  (QPTS / 2)          // 128 two-point packs
#define PBLK   128                 // threads in part kernel
#define OWN_PT 16                  // own points per thread
#define OWN_PB (PBLK * OWN_PT)     // 2048 own points per block
#define CH_PB  (NPTS / OWN_PB)     // 2 own chunks per (dir,b)
#define TOT    (2 * B_SZ * NPTS)   // 131072 own points both directions
#define BLK    256                 // threads elsewhere

// packed fp32 fma: d.lo = a.lo*b.lo + c.lo ; d.hi = a.hi*b.hi + c.hi
__device__ __forceinline__ f32x2 pk_fma(f32x2 a, f32x2 b, f32x2 c) {
    f32x2 d;
    asm("v_pk_fma_f32 %0, %1, %2, %3" : "=v"(d) : "v"(a), "v"(b), "v"(c));
    return d;
}

// ---------------- main kernel: partial mins over one opp-slice ---------------
// grid.x = B * CH_PB * QN = 512, grid.y = 2 (direction)
// LDS: sA[p]={a0,a1,b0,b1} sB[p]={c0,c1,e0,e1} for opp points 2p,2p+1,
// (a,b,c,e) = (-2x,-2y,-2z,|t|^2). Pair cost: 1.5 pk_fma + 0.5 min3.
// Each ds_read_b128 is amortized over 16 own points -> DS ~7-10us < VALU 13.7us.
__global__ __launch_bounds__(PBLK, 2) void chamfer_part(
    const float* __restrict__ pred, const float* __restrict__ target,
    unsigned* __restrict__ wsMin)
{
    __shared__ float4 sA[NPACK];   // 2 KB
    __shared__ float4 sB[NPACK];   // 2 KB

    const int dir = blockIdx.y;
    const float* own = dir ? target : pred;
    const float* opp = dir ? pred : target;

    const int bx    = blockIdx.x;
    const int b     = bx >> 5;                 // CH_PB*QN = 32 blocks/batch
    const int chunk = (bx >> 4) & (CH_PB - 1);
    const int q     = bx & (QN - 1);
    const int tid   = threadIdx.x;

    // ---- stage slice q of the opposite set (1 pack per thread) ----
    const float* oppB = opp + ((size_t)b * NPTS + q * QPTS) * 3;
    for (int p = tid; p < NPACK; p += PBLK) {
        const float* o = oppB + 6 * p;
        float x0 = o[0], y0 = o[1], z0 = o[2];
        float x1 = o[3], y1 = o[4], z1 = o[5];
        sA[p] = make_float4(-2.f * x0, -2.f * x1, -2.f * y0, -2.f * y1);
        sB[p] = make_float4(-2.f * z0, -2.f * z1,
                            fmaf(z0, z0, fmaf(y0, y0, x0 * x0)),
                            fmaf(z1, z1, fmaf(y1, y1, x1 * x1)));
    }
    __syncthreads();

    // ---- 16 own points per thread, coords as broadcast pairs ----
    const int i0 = chunk * OWN_PB + tid;
    f32x2 px2[OWN_PT], py2[OWN_PT], pz2[OWN_PT];
    float p2[OWN_PT], m[OWN_PT];
    #pragma unroll
    for (int k = 0; k < OWN_PT; ++k) {
        const float* op = own + ((size_t)b * NPTS + i0 + k * PBLK) * 3;
        float x = op[0], y = op[1], z = op[2];
        px2[k] = {x, x}; py2[k] = {y, y}; pz2[k] = {z, z};
        p2[k] = fmaf(z, z, fmaf(y, y, x * x));
        m[k]  = 1e30f;
    }

    // ---- min over the slice: 2 packs (4 opp points) per iteration ----
    for (int p = 0; p < NPACK; p += 2) {
        float4 f0 = sA[p],     g0 = sB[p];
        float4 f1 = sA[p + 1], g1 = sB[p + 1];
        f32x2 a0 = {f0.x, f0.y}, b0 = {f0.z, f0.w};
        f32x2 c0 = {g0.x, g0.y}, e0 = {g0.z, g0.w};
        f32x2 a1 = {f1.x, f1.y}, b1 = {f1.z, f1.w};
        f32x2 c1 = {g1.x, g1.y}, e1 = {g1.z, g1.w};
        #pragma unroll
        for (int k = 0; k < OWN_PT; ++k) {
            f32x2 t = pk_fma(c0, pz2[k], e0);
            t = pk_fma(b0, py2[k], t);
            t = pk_fma(a0, px2[k], t);
            m[k] = fminf(fminf(t.x, t.y), m[k]);   // -> v_min3_f32
            f32x2 u = pk_fma(c1, pz2[k], e1);
            u = pk_fma(b1, py2[k], u);
            u = pk_fma(a1, px2[k], u);
            m[k] = fminf(fminf(u.x, u.y), m[k]);
        }
    }

    // ---- combine across slices via order-preserving uint atomicMin ----
    // values are clamped to >=0 so the float<->uint order mapping is monotone
    unsigned* wq = wsMin + ((size_t)dir * B_SZ + b) * NPTS;
    #pragma unroll
    for (int k = 0; k < OWN_PT; ++k) {
        float v = fmaxf(m[k] + p2[k], 0.0f);   // +p2 commutes with slice-min
        atomicMin(wq + i0 + k * PBLK, __float_as_uint(v));
    }
}

// ---------------- combine kernel: mean-reduce the per-point mins -------------
__global__ __launch_bounds__(BLK) void chamfer_combine(
    const unsigned* __restrict__ wsMin, float* __restrict__ out)
{
    const int idx = blockIdx.x * BLK + threadIdx.x;   // 0 .. TOT-1
    float v = __uint_as_float(wsMin[idx]);

    for (int off = 32; off > 0; off >>= 1)
        v += __shfl_down(v, off, 64);

    __shared__ float red[4];
    const int tid = threadIdx.x;
    if ((tid & 63) == 0) red[tid >> 6] = v;
    __syncthreads();
    if (tid == 0) {
        float s = (red[0] + red[1]) + (red[2] + red[3]);
        atomicAdd(out, s * (1.0f / ((float)B_SZ * (float)NPTS)));
    }
}

// ---------------- fallback (round-1 kernel) if ws too small ------------------
__global__ __launch_bounds__(BLK) void chamfer_kernel(
    const float* __restrict__ pred, const float* __restrict__ target,
    float* __restrict__ out)
{
    __shared__ float4 sOpp[NPTS];

    const int dir = blockIdx.y;
    const float* own = (dir == 0) ? pred : target;
    const float* opp = (dir == 0) ? target : pred;

    const int b     = blockIdx.x >> 4;
    const int chunk = blockIdx.x & 15;
    const int tid   = threadIdx.x;

    const float* oppB = opp + (size_t)b * NPTS * 3;
    for (int j = tid; j < NPTS; j += BLK) {
        float x = oppB[3 * j + 0];
        float y = oppB[3 * j + 1];
        float z = oppB[3 * j + 2];
        sOpp[j] = make_float4(-2.0f * x, -2.0f * y, -2.0f * z,
                              fmaf(z, z, fmaf(y, y, x * x)));
    }
    __syncthreads();

    const int i = chunk * BLK + tid;
    const float* op = own + ((size_t)b * NPTS + i) * 3;
    const float px = op[0], py = op[1], pz = op[2];
    const float p2 = fmaf(pz, pz, fmaf(py, py, px * px));

    float m0 = 1e30f, m1 = 1e30f, m2 = 1e30f, m3 = 1e30f;
    for (int j = 0; j < NPTS; j += 8) {
        float4 t0 = sOpp[j + 0];
        float4 t1 = sOpp[j + 1];
        float4 t2 = sOpp[j + 2];
        float4 t3 = sOpp[j + 3];
        float4 t4 = sOpp[j + 4];
        float4 t5 = sOpp[j + 5];
        float4 t6 = sOpp[j + 6];
        float4 t7 = sOpp[j + 7];
        m0 = fminf(m0, fmaf(t0.x, px, fmaf(t0.y, py, fmaf(t0.z, pz, t0.w))));
        m1 = fminf(m1, fmaf(t1.x, px, fmaf(t1.y, py, fmaf(t1.z, pz, t1.w))));
        m2 = fminf(m2, fmaf(t2.x, px, fmaf(t2.y, py, fmaf(t2.z, pz, t2.w))));
        m3 = fminf(m3, fmaf(t3.x, px, fmaf(t3.y, py, fmaf(t3.z, pz, t3.w))));
        m0 = fminf(m0, fmaf(t4.x, px, fmaf(t4.y, py, fmaf(t4.z, pz, t4.w))));
        m1 = fminf(m1, fmaf(t5.x, px, fmaf(t5.y, py, fmaf(t5.z, pz, t5.w))));
        m2 = fminf(m2, fmaf(t6.x, px, fmaf(t6.y, py, fmaf(t6.z, pz, t6.w))));
        m3 = fminf(m3, fmaf(t7.x, px, fmaf(t7.y, py, fmaf(t7.z, pz, t7.w))));
    }
    float v = fminf(fminf(m0, m1), fminf(m2, m3)) + p2;

    for (int off = 32; off > 0; off >>= 1)
        v += __shfl_down(v, off, 64);

    __syncthreads();
    float* red = (float*)sOpp;
    if ((tid & 63) == 0) red[tid >> 6] = v;
    __syncthreads();
    if (tid == 0) {
        float s = (red[0] + red[1]) + (red[2] + red[3]);
        atomicAdd(out, s * (1.0f / ((float)B_SZ * (float)NPTS)));
    }
}

extern "C" void kernel_launch(void* const* d_in, const int* in_sizes, int n_in,
                              void* d_out, int out_size, void* d_ws, size_t ws_size,
                              hipStream_t stream) {
    const float* pred   = (const float*)d_in[0];
    const float* target = (const float*)d_in[1];
    float* out = (float*)d_out;

    hipMemsetAsync(out, 0, sizeof(float), stream);

    const size_t ws_needed = (size_t)TOT * sizeof(unsigned);  // 512 KB
    if (ws_size >= ws_needed) {
        unsigned* ws = (unsigned*)d_ws;
        // 0x7F7F7F7F == 3.39e38f -> "infinity" sentinel for the uint-min trick
        hipMemsetAsync(ws, 0x7F, ws_needed, stream);
        dim3 grid1(B_SZ * CH_PB * QN, 2);          // 512 x 2 = 1024 blocks
        chamfer_part<<<grid1, PBLK, 0, stream>>>(pred, target, ws);
        chamfer_combine<<<TOT / BLK, BLK, 0, stream>>>(ws, out);
    } else {
        dim3 grid(B_SZ * (NPTS / BLK), 2);
        chamfer_kernel<<<grid, BLK, 0, stream>>>(pred, target, out);
    }
}